// Round 5
// baseline (587.035 us; speedup 1.0000x reference)
//
#include <hip/hip_runtime.h>
#include <hip/hip_bf16.h>
#include <stdint.h>

// y = x @ quant(w).T + bias
//   x: (8192, 4096) fp32   w: (4096, 4096) fp32 (OUT, IN)   bias: (4096,) fp32
// R7: register-level software pipelining. Fragment ds_reads issue ONE PHASE
// BEFORE their consuming MFMA burst (read-ahead rotation), so LDS drain hides
// under MFMA. No explicit lgkmcnt drains (compiler emits fine-grained waits).
// 2 barriers + 1 counted vmcnt per K-tile.

using short8  = __attribute__((ext_vector_type(8))) short;   // 8 bf16 = 4 VGPR
using float4v = __attribute__((ext_vector_type(4))) float;   // 4 fp32

// ---------- helpers ----------

__device__ __forceinline__ unsigned short f2bf(float f) {
    union { float f; uint32_t u; } v; v.f = f;
    uint32_t u = v.u;
    u += 0x7fffu + ((u >> 16) & 1u);   // RNE
    return (unsigned short)(u >> 16);
}

__device__ __forceinline__ void gload_lds16(const unsigned short* g, unsigned short* l) {
    __builtin_amdgcn_global_load_lds(
        (const __attribute__((address_space(1))) void*)g,
        (__attribute__((address_space(3))) void*)l,
        16, 0, 0);
}

// ---------- pre-pass 1: absmax(w) (blocks [0,ab)) + cvt x->bf16 (blocks [ab,grid)) ----------

#define AB 1024
#define CB 2048

__global__ void prep_kernel(const float* __restrict__ w, int wn4, int ab_blocks,
                            const float4* __restrict__ x, ushort4* __restrict__ xb, int xn4,
                            unsigned int* __restrict__ amax_out) {
    if ((int)blockIdx.x < ab_blocks) {
        const float4* w4 = (const float4*)w;
        float m = 0.f;
        for (int i = blockIdx.x * blockDim.x + threadIdx.x; i < wn4; i += ab_blocks * blockDim.x) {
            float4 v = w4[i];
            m = fmaxf(m, fmaxf(fmaxf(fabsf(v.x), fabsf(v.y)), fmaxf(fabsf(v.z), fabsf(v.w))));
        }
        #pragma unroll
        for (int off = 32; off > 0; off >>= 1)
            m = fmaxf(m, __shfl_down(m, off, 64));
        __shared__ float smax[4];
        int lane = threadIdx.x & 63, wv = threadIdx.x >> 6;
        if (lane == 0) smax[wv] = m;
        __syncthreads();
        if (threadIdx.x == 0) {
            float bm = fmaxf(fmaxf(smax[0], smax[1]), fmaxf(smax[2], smax[3]));
            atomicMax(amax_out, __float_as_uint(bm));  // vals >= 0: uint order == float order
        }
    } else {
        const int cvt_blocks = gridDim.x - ab_blocks;
        for (int i = ((int)blockIdx.x - ab_blocks) * blockDim.x + threadIdx.x; i < xn4;
             i += cvt_blocks * blockDim.x) {
            float4 v = x[i];
            ushort4 o;
            o.x = f2bf(v.x); o.y = f2bf(v.y); o.z = f2bf(v.z); o.w = f2bf(v.w);
            xb[i] = o;
        }
    }
}

// ---------- pre-pass 2: quantize/dequant w -> bf16 ----------

__global__ void quant_kernel(const float* __restrict__ w, int n4,
                             const unsigned int* __restrict__ amax_bits,
                             ushort4* __restrict__ wq) {
    const float amax  = __uint_as_float(*amax_bits);
    const float scale = amax / 127.0f;
    const float inv   = 1.0f / scale;
    const float4* w4 = (const float4*)w;
    for (int i = blockIdx.x * blockDim.x + threadIdx.x; i < n4; i += gridDim.x * blockDim.x) {
        float4 v = w4[i];
        float q0 = fminf(fmaxf(rintf(v.x * inv), -127.f), 127.f);
        float q1 = fminf(fmaxf(rintf(v.y * inv), -127.f), 127.f);
        float q2 = fminf(fmaxf(rintf(v.z * inv), -127.f), 127.f);
        float q3 = fminf(fmaxf(rintf(v.w * inv), -127.f), 127.f);
        ushort4 o;
        o.x = f2bf(q0 * scale); o.y = f2bf(q1 * scale);
        o.z = f2bf(q2 * scale); o.w = f2bf(q3 * scale);
        wq[i] = o;
    }
}

// ---------- GEMM: C(MxN) = A(MxK) * B(NxK)^T + bias ----------
// 256x256 tile, BK=64, 512 threads (2x4 waves), per-wave 128x64 output
// (acc[8][4] of 16x16 frags). LDS: 2 buffers x (A[2 regions][128][64] +
// B likewise) bf16 = 128 KB.
//
// Swizzle: LDS position (row r, 16B-chunk ch) holds global chunk ch ^ (r&7);
// gload_lds dest linear, global source pre-swizzled, reads apply same XOR.
//
// Stage units (16KB = 2 gloads/thread): u1=A rows[0,64) both regions,
// u2=B rows[0,32) each slice, u3=B rows[32,64), u4=A rows[64,128).
//
// Pipelined tile T (reads buf b=T&1; frags: aLo/bLo preloaded last tile):
//   P1: read bHi=B1(T)   | stage u3,u4(T+1)->b^1 | MFMA Q00(aLo,bLo)
//   P2: read aHi=A1(T)   |                       | MFMA Q01(aLo,bHi) | BARF
//   P3: stage u1(T+2)->b (A0 dead since P2-BARF) | MFMA Q10(aHi,bLo)
//   P4: stage u2(T+2)->b | VM4 BARF | read-ahead aLo,bLo(T+1) from b^1
//                                               | MFMA Q11(aHi,bHi)
// Hazards: every ds_read completes before its first consuming MFMA
// (compiler lgkm wait) which precedes the P2-end barrier, which precedes
// the P3/P4 overwrites of A0/B0. VM4 at P4 retires u1..u4(T+1) (leaves
// u1,u2(T+2) in flight); fences on VM4/BARF pin the IR loads.
// Tail: tile NT-2 ends VM0; tile NT-1 stages/reads nothing.

#define HFE  8192     // elements per 128x64 region
#define BUFE 16384    // elements per buffer (A or B): 2 regions

#define VM4  asm volatile("s_waitcnt vmcnt(4)"  ::: "memory")
#define VM0  asm volatile("s_waitcnt vmcnt(0)"  ::: "memory")
#define VMNONE asm volatile("" ::: "memory")
#define BARF do { asm volatile("" ::: "memory"); __builtin_amdgcn_s_barrier(); \
                  asm volatile("" ::: "memory"); } while (0)

__global__ __launch_bounds__(512, 2) void gemm_bt(
    const unsigned short* __restrict__ A,   // M x K bf16
    const unsigned short* __restrict__ B,   // N x K bf16
    const float* __restrict__ bias,
    float* __restrict__ C,                  // M x N fp32
    int M, int N, int K)
{
    __shared__ __align__(16) unsigned short As[2 * BUFE];   // 64 KB
    __shared__ __align__(16) unsigned short Bs[2 * BUFE];   // 64 KB

    const int tid = threadIdx.x;
    const int l   = tid & 63;
    const int w   = tid >> 6;        // wave 0..7
    const int wm  = w >> 2;          // 0..1 : which 128-row A region this wave reads
    const int wn  = w & 3;           // 0..3 : which 64-row B slice

    // bijective XCD swizzle of flattened block id (nwg % 8 == 0 here)
    const int nbx = gridDim.x;
    int flat = blockIdx.y * nbx + blockIdx.x;
    const int cpx = (nbx * gridDim.y) >> 3;
    flat = (flat & 7) * cpx + (flat >> 3);
    const int bm = (flat / nbx) * 256;
    const int bn = (flat % nbx) * 256;

    // --- staging constants ---
    const int lq  = l >> 3;                         // 0..7
    const int gch = (l & 7) ^ (lq & 7);             // inverse-swizzled source chunk

    const int a_grow = (w >> 2) * 128 + (w & 3) * 16 + lq;          // global tile row
    const int a_base = (w >> 2) * HFE + (w & 3) * 1024;             // LDS elems (uniform)
    const int b_grow = (w >> 2) * 128 + ((w >> 1) & 1) * 64 + (w & 1) * 16 + lq;
    const int b_base = (w >> 2) * HFE + ((w >> 1) & 1) * 4096 + (w & 1) * 1024;

    const unsigned short* aS0 = A + (size_t)(bm + a_grow) * K + gch * 8;
    const unsigned short* bS0 = B + (size_t)(bn + b_grow) * K + gch * 8;

#define STAGE_AU(NB, U, KT) do { \
    const unsigned short* s_ = aS0 + (size_t)(U) * 64 * K + (size_t)(KT) * 64; \
    unsigned short* d_ = As + (NB) * BUFE + a_base + (U) * 4096; \
    gload_lds16(s_, d_); gload_lds16(s_ + 8 * (size_t)K, d_ + 512); } while (0)
#define STAGE_BU(NB, U, KT) do { \
    const unsigned short* s_ = bS0 + (size_t)(U) * 32 * K + (size_t)(KT) * 64; \
    unsigned short* d_ = Bs + (NB) * BUFE + b_base + (U) * 2048; \
    gload_lds16(s_, d_); gload_lds16(s_ + 8 * (size_t)K, d_ + 512); } while (0)

    // --- fragment read: row r = frag*16 + (l&15); chunk ((ks<<2)|quad) ^ (r&7) ---
    const int lr   = l & 15;
    const int quad = l >> 4;
    const int c0   = (quad ^ (l & 7)) * 8;          // ks=0 element offset within row
    const int c1   = ((quad ^ (l & 7)) ^ 4) * 8;    // ks=1
    const unsigned short* paB = As + wm * HFE + lr * 64;
    const unsigned short* pbB = Bs + (wn >> 1) * HFE + (wn & 1) * 4096 + lr * 64;

    float4v acc[8][4];
    const float4v zero = {0.f, 0.f, 0.f, 0.f};
    #pragma unroll
    for (int i = 0; i < 8; i++)
        #pragma unroll
        for (int j = 0; j < 4; j++) acc[i][j] = zero;

    short8 aLo[4][2], aHi[4][2], bLo[2][2], bHi[2][2];

// read A frags (MH half: 0 -> rows[0,64) = u1 data, 1 -> rows[64,128) = u4)
#define RD_A(DST, PA, MH) do { _Pragma("unroll") \
    for (int i_ = 0; i_ < 4; i_++) { \
        DST[i_][0] = *(const short8*)((PA) + ((MH) * 4 + i_) * 1024 + c0); \
        DST[i_][1] = *(const short8*)((PA) + ((MH) * 4 + i_) * 1024 + c1); } } while (0)
// read B frags (NH half: 0 -> rows[0,32) = u2 data, 1 -> rows[32,64) = u3)
#define RD_B(DST, PB, NH) do { _Pragma("unroll") \
    for (int j_ = 0; j_ < 2; j_++) { \
        DST[j_][0] = *(const short8*)((PB) + ((NH) * 2 + j_) * 1024 + c0); \
        DST[j_][1] = *(const short8*)((PB) + ((NH) * 2 + j_) * 1024 + c1); } } while (0)
// MFMA quadrant: acc[MH*4+i][NH*2+j] += AF[i] x BF[j] over both k-slices
#define MMA_Q(AF, BF, MH, NH) do { \
    __builtin_amdgcn_s_setprio(1); \
    _Pragma("unroll") for (int i_ = 0; i_ < 4; i_++) \
    _Pragma("unroll") for (int j_ = 0; j_ < 2; j_++) { \
        acc[(MH)*4+i_][(NH)*2+j_] = __builtin_amdgcn_mfma_f32_16x16x32_bf16( \
            AF[i_][0], BF[j_][0], acc[(MH)*4+i_][(NH)*2+j_], 0, 0, 0); \
        acc[(MH)*4+i_][(NH)*2+j_] = __builtin_amdgcn_mfma_f32_16x16x32_bf16( \
            AF[i_][1], BF[j_][1], acc[(MH)*4+i_][(NH)*2+j_], 0, 0, 0); } \
    __builtin_amdgcn_s_setprio(0); } while (0)

// One K-tile, software-pipelined. CB_ = buffer of tile kt; frags aLo/bLo
// for THIS tile were loaded during the previous tile's P4 (or prologue).
// PRE12: stage u3,u4(kt+1); PRE34: stage u1,u2(kt+2); ENDW: tile-end vm wait;
// RA: read-ahead aLo/bLo of kt+1 from buf CB_^1.
#define GEMM_TILE(CB_, PRE12, PRE34, ENDW, RA) do { \
    const unsigned short* pa_ = paB + (CB_) * BUFE; \
    const unsigned short* pb_ = pbB + (CB_) * BUFE; \
    const unsigned short* paN_ = paB + ((CB_) ^ 1) * BUFE; \
    const unsigned short* pbN_ = pbB + ((CB_) ^ 1) * BUFE; \
    /* P1 */ \
    RD_B(bHi, pb_, 1); \
    if (PRE12) { STAGE_BU((CB_) ^ 1, 1, kt + 1); STAGE_AU((CB_) ^ 1, 1, kt + 1); } \
    MMA_Q(aLo, bLo, 0, 0); \
    /* P2 */ \
    RD_A(aHi, pa_, 1); \
    MMA_Q(aLo, bHi, 0, 1); \
    BARF; \
    /* P3 */ \
    if (PRE34) STAGE_AU(CB_, 0, kt + 2); \
    MMA_Q(aHi, bLo, 1, 0); \
    /* P4 */ \
    if (PRE34) STAGE_BU(CB_, 0, kt + 2); \
    ENDW; BARF; \
    if (RA) { RD_A(aLo, paN_, 0); RD_B(bLo, pbN_, 0); } \
    MMA_Q(aHi, bHi, 1, 1); \
} while (0)

    // prologue: u1(0),u2(0),u3(0),u4(0) -> buf0; u1(1),u2(1) -> buf1.
    // VM4 retires all of tile 0 (leaves u1,u2(1) in flight = steady invariant).
    STAGE_AU(0, 0, 0); STAGE_BU(0, 0, 0);
    STAGE_BU(0, 1, 0); STAGE_AU(0, 1, 0);
    STAGE_AU(1, 0, 1); STAGE_BU(1, 0, 1);
    VM4; BARF;
    RD_A(aLo, paB, 0); RD_B(bLo, pbB, 0);   // tile 0 Q00 frags from buf0

    const int NT = K >> 6;                 // = 64
    int kt = 0, cb = 0;
    for (; kt < NT - 2; ++kt, cb ^= 1)
        GEMM_TILE(cb, 1, 1, VM4, 1);
    GEMM_TILE(cb, 1, 0, VM0, 1); ++kt; cb ^= 1;   // tile NT-2: drain all
    GEMM_TILE(cb, 0, 0, VMNONE, 0);               // tile NT-1: nothing in flight

    // --- epilogue: C/D layout col=lane&15, row=(lane>>4)*4+reg ---
    #pragma unroll
    for (int j = 0; j < 4; j++) {
        const int gc = bn + wn * 64 + j * 16 + lr;
        const float bs = bias[gc];
        #pragma unroll
        for (int i = 0; i < 8; i++) {
            const int gr = bm + wm * 128 + i * 16 + quad * 4;
            float* cp = C + (size_t)gr * N + gc;
            #pragma unroll
            for (int r = 0; r < 4; r++)
                cp[(size_t)r * N] = acc[i][j][r] + bs;
        }
    }
}

// ---------- launch ----------

extern "C" void kernel_launch(void* const* d_in, const int* in_sizes, int n_in,
                              void* d_out, int out_size, void* d_ws, size_t ws_size,
                              hipStream_t stream) {
    const float* x    = (const float*)d_in[0];   // (M, K)
    const float* w    = (const float*)d_in[1];   // (N, K)
    const float* bias = (const float*)d_in[2];   // (N,)
    float* out = (float*)d_out;

    const int N = 4096, K = 4096;
    const int M = in_sizes[0] / K;               // 8192

    // workspace: [256B amax | wq bf16 N*K | xb bf16 chunk]
    const size_t wq_off   = 256;
    const size_t wq_bytes = (size_t)N * K * 2;
    unsigned int*   amax = (unsigned int*)d_ws;
    unsigned short* wq   = (unsigned short*)((char*)d_ws + wq_off);
    unsigned short* xb   = (unsigned short*)((char*)d_ws + wq_off + wq_bytes);

    size_t avail = (ws_size > wq_off + wq_bytes) ? ws_size - wq_off - wq_bytes : 0;
    int nch = 1;
    while (nch < 32 && (size_t)(M / nch) * K * 2 > avail) nch <<= 1;
    const int crows = M / nch;                   // multiple of 256 for M=8192, nch<=32

    hipMemsetAsync(d_ws, 0, 256, stream);

    if (nch == 1) {
        prep_kernel<<<AB + CB, 256, 0, stream>>>(w, (N * K) / 4, AB,
                                                 (const float4*)x, (ushort4*)xb, (M * K) / 4,
                                                 amax);
        quant_kernel<<<2048, 256, 0, stream>>>(w, (N * K) / 4, amax, (ushort4*)wq);
        dim3 grid(N / 256, M / 256);
        gemm_bt<<<grid, 512, 0, stream>>>(xb, wq, bias, out, M, N, K);
    } else {
        prep_kernel<<<AB, 256, 0, stream>>>(w, (N * K) / 4, AB,
                                            (const float4*)x, (ushort4*)xb, 0, amax);
        quant_kernel<<<2048, 256, 0, stream>>>(w, (N * K) / 4, amax, (ushort4*)wq);
        for (int c = 0; c < nch; c++) {
            const float* xc = x + (size_t)c * crows * K;
            prep_kernel<<<CB, 256, 0, stream>>>(nullptr, 0, 0,
                                                (const float4*)xc, (ushort4*)xb,
                                                (crows * K) / 4, amax);
            dim3 grid(N / 256, crows / 256);
            gemm_bt<<<grid, 512, 0, stream>>>(xb, wq, bias, out + (size_t)c * crows * N,
                                              crows, N, K);
        }
    }
}

// Round 6
// 550.520 us; speedup vs baseline: 1.0663x; 1.0663x over previous
//
#include <hip/hip_runtime.h>
#include <hip/hip_bf16.h>
#include <stdint.h>

// y = x @ quant(w).T + bias
//   x: (8192, 4096) fp32   w: (4096, 4096) fp32 (OUT, IN)   bias: (4096,) fp32
// R8: R4's exact schedule (best measured: 303.6 us) with NAKED sync idiom
// (m201-verbatim): raw s_barrier, asm waitcnt WITHOUT "memory" clobbers,
// optional lgkmcnt(8) before the 12-read phase's barrier. The "memory"
// clobbers were total compiler-scheduling walls at every phase boundary,
// forbidding the cross-phase read/MFMA pipeline the m201 template forms.

using short8  = __attribute__((ext_vector_type(8))) short;   // 8 bf16 = 4 VGPR
using float4v = __attribute__((ext_vector_type(4))) float;   // 4 fp32

// ---------- helpers ----------

__device__ __forceinline__ unsigned short f2bf(float f) {
    union { float f; uint32_t u; } v; v.f = f;
    uint32_t u = v.u;
    u += 0x7fffu + ((u >> 16) & 1u);   // RNE
    return (unsigned short)(u >> 16);
}

__device__ __forceinline__ void gload_lds16(const unsigned short* g, unsigned short* l) {
    __builtin_amdgcn_global_load_lds(
        (const __attribute__((address_space(1))) void*)g,
        (__attribute__((address_space(3))) void*)l,
        16, 0, 0);
}

// ---------- pre-pass 1: absmax(w) (blocks [0,ab)) + cvt x->bf16 (blocks [ab,grid)) ----------

#define AB 1024
#define CB 2048

__global__ void prep_kernel(const float* __restrict__ w, int wn4, int ab_blocks,
                            const float4* __restrict__ x, ushort4* __restrict__ xb, int xn4,
                            unsigned int* __restrict__ amax_out) {
    if ((int)blockIdx.x < ab_blocks) {
        const float4* w4 = (const float4*)w;
        float m = 0.f;
        for (int i = blockIdx.x * blockDim.x + threadIdx.x; i < wn4; i += ab_blocks * blockDim.x) {
            float4 v = w4[i];
            m = fmaxf(m, fmaxf(fmaxf(fabsf(v.x), fabsf(v.y)), fmaxf(fabsf(v.z), fabsf(v.w))));
        }
        #pragma unroll
        for (int off = 32; off > 0; off >>= 1)
            m = fmaxf(m, __shfl_down(m, off, 64));
        __shared__ float smax[4];
        int lane = threadIdx.x & 63, wv = threadIdx.x >> 6;
        if (lane == 0) smax[wv] = m;
        __syncthreads();
        if (threadIdx.x == 0) {
            float bm = fmaxf(fmaxf(smax[0], smax[1]), fmaxf(smax[2], smax[3]));
            atomicMax(amax_out, __float_as_uint(bm));  // vals >= 0: uint order == float order
        }
    } else {
        const int cvt_blocks = gridDim.x - ab_blocks;
        for (int i = ((int)blockIdx.x - ab_blocks) * blockDim.x + threadIdx.x; i < xn4;
             i += cvt_blocks * blockDim.x) {
            float4 v = x[i];
            ushort4 o;
            o.x = f2bf(v.x); o.y = f2bf(v.y); o.z = f2bf(v.z); o.w = f2bf(v.w);
            xb[i] = o;
        }
    }
}

// ---------- pre-pass 2: quantize/dequant w -> bf16 ----------

__global__ void quant_kernel(const float* __restrict__ w, int n4,
                             const unsigned int* __restrict__ amax_bits,
                             ushort4* __restrict__ wq) {
    const float amax  = __uint_as_float(*amax_bits);
    const float scale = amax / 127.0f;
    const float inv   = 1.0f / scale;
    const float4* w4 = (const float4*)w;
    for (int i = blockIdx.x * blockDim.x + threadIdx.x; i < n4; i += gridDim.x * blockDim.x) {
        float4 v = w4[i];
        float q0 = fminf(fmaxf(rintf(v.x * inv), -127.f), 127.f);
        float q1 = fminf(fmaxf(rintf(v.y * inv), -127.f), 127.f);
        float q2 = fminf(fmaxf(rintf(v.z * inv), -127.f), 127.f);
        float q3 = fminf(fmaxf(rintf(v.w * inv), -127.f), 127.f);
        ushort4 o;
        o.x = f2bf(q0 * scale); o.y = f2bf(q1 * scale);
        o.z = f2bf(q2 * scale); o.w = f2bf(q3 * scale);
        wq[i] = o;
    }
}

// ---------- GEMM: C(MxN) = A(MxK) * B(NxK)^T + bias ----------
// 256x256 tile, BK=64, 512 threads (2x4 waves), per-wave 128x64 output
// (acc[8][4] of 16x16 frags). LDS: 2 buffers x (A[2 regions][128][64] +
// B likewise) bf16 = 128 KB.
//
// Swizzle: LDS position (row r, 16B-chunk ch) holds global chunk ch ^ (r&7).
// gload_lds writes linearly -> pre-swizzle the GLOBAL source chunk index;
// ds_read applies the same XOR. Every stage unit keeps r&7 = (l>>3), so one
// formula gch = (l&7)^((l>>3)&7) serves all units.
//
// Stage units (16KB = 2 gloads/thread each) == per-phase read unions:
//   u1 SU_A0: rows [0,64)  of both A regions      (P1 A reads)
//   u2 SU_B0: rows [0,32)  of each B slice        (P1 B reads)
//   u3 SU_B1: rows [32,64) of each B slice        (P2 B reads)
//   u4 SU_A1: rows [64,128) of both A regions     (P3 A reads)
//
// Schedule identical to R4 (refcheck'd, 303.6 us): per tile T,
//   P1: read u1,u2 data | stage u1,u2(T+1) | lgk8 | BAR lgk0 MMA Q00 | vm6 BAR
//   P2: read u3 data    | stage u3(T+1)           | BAR lgk0 MMA Q01 | vm6 BAR
//   P3: read u4 data    | stage u4(T+1)           | BAR lgk0 MMA Q10 | BAR
//   P4: (regs only)                               | BAR lgk0 MMA Q11 | vm4 BAR
// ONLY change vs R4: all syncs are NAKED (no "memory" clobbers, raw
// s_barrier) so the compiler may pipeline reads/MFMA across phases.
// Correctness: each ds_read is pinned before the next barrier by its MFMA
// use; reads can't hoist above gload_lds calls (LDS alias); vmcnt ledger
// unchanged (VM6->u3 of T landed, VM6->u4 of T, VM4->u1,u2 of T+1).

#define HFE  8192     // elements per 128x64 region
#define BUFE 16384    // elements per buffer (A or B): 2 regions

#define VM6  asm volatile("s_waitcnt vmcnt(6)")
#define VM4  asm volatile("s_waitcnt vmcnt(4)")
#define VM2  asm volatile("s_waitcnt vmcnt(2)")
#define VM0  asm volatile("s_waitcnt vmcnt(0)")
#define VMNONE ((void)0)
#define LGK0 asm volatile("s_waitcnt lgkmcnt(0)")
#define LGK8 asm volatile("s_waitcnt lgkmcnt(8)")
#define BAR  __builtin_amdgcn_s_barrier()

__global__ __launch_bounds__(512, 2) void gemm_bt(
    const unsigned short* __restrict__ A,   // M x K bf16
    const unsigned short* __restrict__ B,   // N x K bf16
    const float* __restrict__ bias,
    float* __restrict__ C,                  // M x N fp32
    int M, int N, int K)
{
    __shared__ __align__(16) unsigned short As[2 * BUFE];   // 64 KB
    __shared__ __align__(16) unsigned short Bs[2 * BUFE];   // 64 KB

    const int tid = threadIdx.x;
    const int l   = tid & 63;
    const int w   = tid >> 6;        // wave 0..7
    const int wm  = w >> 2;          // 0..1 : which 128-row A region this wave reads
    const int wn  = w & 3;           // 0..3 : which 64-row B slice

    // bijective XCD swizzle of flattened block id (nwg % 8 == 0 here)
    const int nbx = gridDim.x;
    int flat = blockIdx.y * nbx + blockIdx.x;
    const int cpx = (nbx * gridDim.y) >> 3;
    flat = (flat & 7) * cpx + (flat >> 3);
    const int bm = (flat / nbx) * 256;
    const int bn = (flat % nbx) * 256;

    // --- staging constants ---
    const int lq  = l >> 3;                         // 0..7
    const int gch = (l & 7) ^ (lq & 7);             // inverse-swizzled source chunk

    // SU_A0: waves 0-3 -> region 0 rows (w&3)*16.., waves 4-7 -> region 1
    const int a_grow = (w >> 2) * 128 + (w & 3) * 16 + lq;          // global tile row
    const int a_base = (w >> 2) * HFE + (w & 3) * 1024;             // LDS elems (uniform)
    // SU_B0: 2 waves per 64-row slice, first 32 rows of each slice
    const int b_grow = (w >> 2) * 128 + ((w >> 1) & 1) * 64 + (w & 1) * 16 + lq;
    const int b_base = (w >> 2) * HFE + ((w >> 1) & 1) * 4096 + (w & 1) * 1024;

    const unsigned short* aS0 = A + (size_t)(bm + a_grow) * K + gch * 8;
    const unsigned short* bS0 = B + (size_t)(bn + b_grow) * K + gch * 8;

#define STAGE_AU(NB, U, KT) do { \
    const unsigned short* s_ = aS0 + (size_t)(U) * 64 * K + (size_t)(KT) * 64; \
    unsigned short* d_ = As + (NB) * BUFE + a_base + (U) * 4096; \
    gload_lds16(s_, d_); gload_lds16(s_ + 8 * (size_t)K, d_ + 512); } while (0)
#define STAGE_BU(NB, U, KT) do { \
    const unsigned short* s_ = bS0 + (size_t)(U) * 32 * K + (size_t)(KT) * 64; \
    unsigned short* d_ = Bs + (NB) * BUFE + b_base + (U) * 2048; \
    gload_lds16(s_, d_); gload_lds16(s_ + 8 * (size_t)K, d_ + 512); } while (0)

    // --- fragment read: row r = frag*16 + (l&15); chunk ((ks<<2)|quad) ^ (r&7) ---
    const int lr   = l & 15;
    const int quad = l >> 4;
    const int c0   = (quad ^ (l & 7)) * 8;          // ks=0 element offset within row
    const int c1   = ((quad ^ (l & 7)) ^ 4) * 8;    // ks=1
    const unsigned short* paB = As + wm * HFE + lr * 64;
    const unsigned short* pbB = Bs + (wn >> 1) * HFE + (wn & 1) * 4096 + lr * 64;

    float4v acc[8][4];
    const float4v zero = {0.f, 0.f, 0.f, 0.f};
    #pragma unroll
    for (int i = 0; i < 8; i++)
        #pragma unroll
        for (int j = 0; j < 4; j++) acc[i][j] = zero;

    short8 aF[4][2], bF0[2][2], bF1[2][2];

#define PH_READ_A(PA, MH) do { _Pragma("unroll") \
    for (int i_ = 0; i_ < 4; i_++) { \
        aF[i_][0] = *(const short8*)((PA) + ((MH) * 4 + i_) * 1024 + c0); \
        aF[i_][1] = *(const short8*)((PA) + ((MH) * 4 + i_) * 1024 + c1); } } while (0)
#define PH_READ_B(PB, NH, BF) do { _Pragma("unroll") \
    for (int j_ = 0; j_ < 2; j_++) { \
        BF[j_][0] = *(const short8*)((PB) + ((NH) * 2 + j_) * 1024 + c0); \
        BF[j_][1] = *(const short8*)((PB) + ((NH) * 2 + j_) * 1024 + c1); } } while (0)
#define PH_MMA(MH, NH, BF) do { \
    __builtin_amdgcn_s_setprio(1); \
    _Pragma("unroll") for (int i_ = 0; i_ < 4; i_++) \
    _Pragma("unroll") for (int j_ = 0; j_ < 2; j_++) { \
        acc[(MH)*4+i_][(NH)*2+j_] = __builtin_amdgcn_mfma_f32_16x16x32_bf16( \
            aF[i_][0], BF[j_][0], acc[(MH)*4+i_][(NH)*2+j_], 0, 0, 0); \
        acc[(MH)*4+i_][(NH)*2+j_] = __builtin_amdgcn_mfma_f32_16x16x32_bf16( \
            aF[i_][1], BF[j_][1], acc[(MH)*4+i_][(NH)*2+j_], 0, 0, 0); } \
    __builtin_amdgcn_s_setprio(0); } while (0)

// 4 phases/K-tile, R4 wait placement, naked syncs.
#define GEMM_TILE(CB_, PRE, VW1, VW2, VW4) do { \
    const unsigned short* pa_ = paB + (CB_) * BUFE; \
    const unsigned short* pb_ = pbB + (CB_) * BUFE; \
    const int nb_ = (CB_) ^ 1; (void)nb_; \
    /* phase 1: Q00 — needs SU_A0 + SU_B0 of current buffer */ \
    PH_READ_A(pa_, 0); PH_READ_B(pb_, 0, bF0); \
    if (PRE) { STAGE_AU(nb_, 0, kt + 1); STAGE_BU(nb_, 0, kt + 1); } \
    LGK8; BAR; LGK0; \
    PH_MMA(0, 0, bF0); \
    VW1; BAR; \
    /* phase 2: Q01 — needs SU_B1 */ \
    PH_READ_B(pb_, 1, bF1); \
    if (PRE) STAGE_BU(nb_, 1, kt + 1); \
    BAR; LGK0; \
    PH_MMA(0, 1, bF1); \
    VW2; BAR; \
    /* phase 3: Q10 — needs SU_A1 */ \
    PH_READ_A(pa_, 1); \
    if (PRE) STAGE_AU(nb_, 1, kt + 1); \
    BAR; LGK0; \
    PH_MMA(1, 0, bF0); \
    BAR; \
    /* phase 4: Q11 — registers only */ \
    BAR; LGK0; \
    PH_MMA(1, 1, bF1); \
    VW4; BAR; \
} while (0)

    // prologue: stage tile 0 in consumption order A0,B0,B1,A1
    STAGE_AU(0, 0, 0); STAGE_BU(0, 0, 0); STAGE_BU(0, 1, 0); STAGE_AU(0, 1, 0);
    VM4; BAR;   // SU_A0,SU_B0 landed (all waves after BAR); B1,A1 may be in flight

    const int NT = K >> 6;
    int kt = 0, cb = 0;
    for (; kt < NT - 1; ++kt, cb ^= 1)
        GEMM_TILE(cb, 1, VM6, VM6, VM4);
    GEMM_TILE(cb, 0, VM2, VM0, VMNONE);   // drain tile: 4 -> 2 -> 0 in flight

    // --- epilogue: C/D layout col=lane&15, row=(lane>>4)*4+reg ---
    #pragma unroll
    for (int j = 0; j < 4; j++) {
        const int gc = bn + wn * 64 + j * 16 + lr;
        const float bs = bias[gc];
        #pragma unroll
        for (int i = 0; i < 8; i++) {
            const int gr = bm + wm * 128 + i * 16 + quad * 4;
            float* cp = C + (size_t)gr * N + gc;
            #pragma unroll
            for (int r = 0; r < 4; r++)
                cp[(size_t)r * N] = acc[i][j][r] + bs;
        }
    }
}

// ---------- launch ----------

extern "C" void kernel_launch(void* const* d_in, const int* in_sizes, int n_in,
                              void* d_out, int out_size, void* d_ws, size_t ws_size,
                              hipStream_t stream) {
    const float* x    = (const float*)d_in[0];   // (M, K)
    const float* w    = (const float*)d_in[1];   // (N, K)
    const float* bias = (const float*)d_in[2];   // (N,)
    float* out = (float*)d_out;

    const int N = 4096, K = 4096;
    const int M = in_sizes[0] / K;               // 8192

    // workspace: [256B amax | wq bf16 N*K | xb bf16 chunk]
    const size_t wq_off   = 256;
    const size_t wq_bytes = (size_t)N * K * 2;
    unsigned int*   amax = (unsigned int*)d_ws;
    unsigned short* wq   = (unsigned short*)((char*)d_ws + wq_off);
    unsigned short* xb   = (unsigned short*)((char*)d_ws + wq_off + wq_bytes);

    size_t avail = (ws_size > wq_off + wq_bytes) ? ws_size - wq_off - wq_bytes : 0;
    int nch = 1;
    while (nch < 32 && (size_t)(M / nch) * K * 2 > avail) nch <<= 1;
    const int crows = M / nch;                   // multiple of 256 for M=8192, nch<=32

    hipMemsetAsync(d_ws, 0, 256, stream);

    if (nch == 1) {
        prep_kernel<<<AB + CB, 256, 0, stream>>>(w, (N * K) / 4, AB,
                                                 (const float4*)x, (ushort4*)xb, (M * K) / 4,
                                                 amax);
        quant_kernel<<<2048, 256, 0, stream>>>(w, (N * K) / 4, amax, (ushort4*)wq);
        dim3 grid(N / 256, M / 256);
        gemm_bt<<<grid, 512, 0, stream>>>(xb, wq, bias, out, M, N, K);
    } else {
        prep_kernel<<<AB, 256, 0, stream>>>(w, (N * K) / 4, AB,
                                            (const float4*)x, (ushort4*)xb, 0, amax);
        quant_kernel<<<2048, 256, 0, stream>>>(w, (N * K) / 4, amax, (ushort4*)wq);
        for (int c = 0; c < nch; c++) {
            const float* xc = x + (size_t)c * crows * K;
            prep_kernel<<<CB, 256, 0, stream>>>(nullptr, 0, 0,
                                                (const float4*)xc, (ushort4*)xb,
                                                (crows * K) / 4, amax);
            dim3 grid(N / 256, crows / 256);
            gemm_bt<<<grid, 512, 0, stream>>>(xb, wq, bias, out + (size_t)c * crows * N,
                                              crows, N, K);
        }
    }
}